// Round 2
// baseline (655.347 us; speedup 1.0000x reference)
//
#include <hip/hip_runtime.h>
#include <math.h>

typedef unsigned short u16;
typedef __attribute__((ext_vector_type(8))) short short8;
typedef __attribute__((ext_vector_type(4))) float f32x4;

#define DI static __device__ __forceinline__

DI float bf2f(u16 u) { union { unsigned u; float f; } c; c.u = (unsigned)u << 16; return c.f; }
DI u16 f2bf(float f) {
  union { float f; unsigned u; } c; c.f = f;
  unsigned r = c.u + 0x7fffu + ((c.u >> 16) & 1u);
  return (u16)(r >> 16);
}

// ---------- weight prep: w[K][N] f32 -> wt[N][K] bf16 (transpose + convert) ----------
__global__ __launch_bounds__(256) void prep_w(const float* __restrict__ w,
                                              u16* __restrict__ wt, int K, int N) {
  __shared__ float tile[32][33];
  int k0 = blockIdx.y * 32, n0 = blockIdx.x * 32;
  int tid = threadIdx.x;
  int ni = tid & 31, ki8 = tid >> 5;
  for (int i = 0; i < 4; i++) {
    int k = ki8 + i * 8;
    tile[k][ni] = w[(size_t)(k0 + k) * N + n0 + ni];
  }
  __syncthreads();
  int kj = tid & 31, nj8 = tid >> 5;
  for (int i = 0; i < 4; i++) {
    int n = nj8 + i * 8;
    wt[(size_t)(n0 + n) * K + k0 + kj] = f2bf(tile[kj][n]);
  }
}

// ---------- generic f32 -> bf16 ----------
__global__ __launch_bounds__(256) void conv_bf16(const float* __restrict__ in,
                                                 u16* __restrict__ out, long n) {
  long i = (long)blockIdx.x * 256 + threadIdx.x;
  if (i < n) out[i] = f2bf(in[i]);
}

// ---------- GroupNorm stats: one block per (b,g), 20*1024 elems ----------
__global__ __launch_bounds__(256) void gn_stats(const float* __restrict__ x,
                                                float* __restrict__ mean_o,
                                                float* __restrict__ rstd_o) {
  int bg = blockIdx.x;
  const float4* p = (const float4*)(x + (size_t)bg * 20480);
  float s = 0.f, sq = 0.f;
  for (int i = threadIdx.x; i < 5120; i += 256) {
    float4 v = p[i];
    s += v.x + v.y + v.z + v.w;
    sq += v.x * v.x + v.y * v.y + v.z * v.z + v.w * v.w;
  }
  for (int off = 1; off < 64; off <<= 1) { s += __shfl_xor(s, off); sq += __shfl_xor(sq, off); }
  __shared__ float ps[4], pq[4];
  int w = threadIdx.x >> 6;
  if ((threadIdx.x & 63) == 0) { ps[w] = s; pq[w] = sq; }
  __syncthreads();
  if (threadIdx.x == 0) {
    float S = ps[0] + ps[1] + ps[2] + ps[3];
    float Q = pq[0] + pq[1] + pq[2] + pq[3];
    float mu = S / 20480.f;
    float var = Q / 20480.f - mu * mu;
    mean_o[bg] = mu;
    rstd_o[bg] = rsqrtf(var + 1e-5f);
  }
}

// ---------- GN apply + transpose (B,C,S) -> bf16 (B*S, C) ----------
__global__ __launch_bounds__(256) void gn_apply(const float* __restrict__ x,
                                                const float* __restrict__ mean_,
                                                const float* __restrict__ rstd_,
                                                const float* __restrict__ g,
                                                const float* __restrict__ bb,
                                                u16* __restrict__ out) {
  __shared__ float tile[32][33];
  int b = blockIdx.z, c0 = blockIdx.y * 32, s0 = blockIdx.x * 32;
  int tid = threadIdx.x;
  int si = tid & 31, ci8 = tid >> 5;
  for (int i = 0; i < 4; i++) {
    int c = c0 + ci8 + i * 8;
    int gg = c / 20;
    float mu = mean_[b * 32 + gg], rs = rstd_[b * 32 + gg];
    float v = x[((size_t)b * 640 + c) * 1024 + s0 + si];
    tile[ci8 + i * 8][si] = (v - mu) * rs * g[c] + bb[c];
  }
  __syncthreads();
  int cj = tid & 31, sj8 = tid >> 5;
  for (int i = 0; i < 4; i++) {
    int sj = sj8 + i * 8;
    out[((size_t)b * 1024 + s0 + sj) * 640 + c0 + cj] = f2bf(tile[cj][sj]);
  }
}

// ---------- LayerNorm: fp32 [T,640] -> bf16 [T,640]; one wave per token ----------
__global__ __launch_bounds__(256) void ln_kernel(const float* __restrict__ in,
                                                 const float* __restrict__ g,
                                                 const float* __restrict__ bb,
                                                 u16* __restrict__ out) {
  int t = blockIdx.x * 4 + (threadIdx.x >> 6);
  int lane = threadIdx.x & 63;
  const float* row = in + (size_t)t * 640;
  float xv[10], s = 0.f, sq = 0.f;
  for (int j = 0; j < 10; j++) {
    xv[j] = row[lane + j * 64];
    s += xv[j];
    sq += xv[j] * xv[j];
  }
  for (int off = 1; off < 64; off <<= 1) { s += __shfl_xor(s, off); sq += __shfl_xor(sq, off); }
  float mu = s * (1.f / 640.f);
  float var = sq * (1.f / 640.f) - mu * mu;
  float rstd = rsqrtf(var + 1e-5f);
  for (int j = 0; j < 10; j++) {
    int c = lane + j * 64;
    out[(size_t)t * 640 + c] = f2bf((xv[j] - mu) * rstd * g[c] + bb[c]);
  }
}

// ---------- GEGLU: proj bf16 [T,5120] -> tg bf16 [T,2560] ----------
__global__ __launch_bounds__(256) void geglu(const u16* __restrict__ proj,
                                             u16* __restrict__ tg) {
  long i = (long)blockIdx.x * 256 + threadIdx.x;
  int t = (int)(i / 320);
  int j8 = (int)(i % 320) * 8;
  short8 av = *(const short8*)(proj + (size_t)t * 5120 + j8);
  short8 gv = *(const short8*)(proj + (size_t)t * 5120 + 2560 + j8);
  short8 o;
  for (int r = 0; r < 8; r++) {
    float a = bf2f((u16)av[r]);
    float gx = bf2f((u16)gv[r]);
    float gl = 0.5f * gx * (1.f + erff(gx * 0.70710678f));
    o[r] = (short)f2bf(a * gl);
  }
  *(short8*)(tg + (size_t)t * 2560 + j8) = o;
}

// ---------- GEMM: C[M,N] = A[M,K](bf16) x Bt[N,K](bf16)^T + bias ----------
// MODE 0: out fp32       MODE 1: out bf16
// MODE 2: out fp32 = acc + bias + res (in-place residual ok)
// MODE 3: final: out fp32 [B,640,1024] at (b,n,s) = acc + bias + x[b,n,s]
template <int MODE>
__global__ __launch_bounds__(256) void gemm_bt(const u16* __restrict__ A,
                                               const u16* __restrict__ Bt,
                                               const float* __restrict__ bias,
                                               void* outp, const float* res,
                                               int M, int N, int K) {
  __shared__ __align__(16) u16 As[128 * 40];
  __shared__ __align__(16) u16 Bs[128 * 40];
  const int tid = threadIdx.x;
  const int lane = tid & 63, wid = tid >> 6;
  const int wm = wid >> 1, wn = wid & 1;
  const int m0 = blockIdx.x * 128, n0 = blockIdx.y * 128;
  const int rq = lane & 15, g4 = lane >> 4;

  f32x4 acc[4][4] = {};

  for (int k0 = 0; k0 < K; k0 += 32) {
    for (int s = tid; s < 512; s += 256) {
      int row = s >> 2, part = s & 3;
      int gm = m0 + row;
      if (gm >= M) gm = M - 1;
      *(short8*)&As[row * 40 + part * 8] = *(const short8*)(A + (size_t)gm * K + k0 + part * 8);
      *(short8*)&Bs[row * 40 + part * 8] =
          *(const short8*)(Bt + (size_t)(n0 + row) * K + k0 + part * 8);
    }
    __syncthreads();
    short8 af[4], bfr[4];
    for (int i = 0; i < 4; i++)
      af[i] = *(const short8*)&As[(wm * 64 + i * 16 + rq) * 40 + g4 * 8];
    for (int j = 0; j < 4; j++)
      bfr[j] = *(const short8*)&Bs[(wn * 64 + j * 16 + rq) * 40 + g4 * 8];
    for (int i = 0; i < 4; i++)
      for (int j = 0; j < 4; j++)
        acc[i][j] = __builtin_amdgcn_mfma_f32_16x16x32_bf16(af[i], bfr[j], acc[i][j], 0, 0, 0);
    __syncthreads();
  }

  for (int j = 0; j < 4; j++) {
    int n = n0 + wn * 64 + j * 16 + rq;
    float bv = bias[n];
    for (int i = 0; i < 4; i++) {
      int mb = m0 + wm * 64 + i * 16 + g4 * 4;
      f32x4 v = acc[i][j];
      if (MODE == 3) {
        int b = mb >> 10, sp = mb & 1023;
        size_t off = ((size_t)b * 640 + n) * 1024 + sp;
        f32x4 xv = *(const f32x4*)(res + off);
        f32x4 o;
        for (int r = 0; r < 4; r++) o[r] = v[r] + bv + xv[r];
        *(f32x4*)((float*)outp + off) = o;
      } else {
        for (int r = 0; r < 4; r++) {
          int m = mb + r;
          if (m >= M) break;
          size_t off = (size_t)m * N + n;
          float val = v[r] + bv;
          if (MODE == 0)
            ((float*)outp)[off] = val;
          else if (MODE == 1)
            ((u16*)outp)[off] = f2bf(val);
          else
            ((float*)outp)[off] = val + res[off];
        }
      }
    }
  }
}

// ---------- flash attention: HD=80 (padded 96), 64 queries/block, 4 waves ----------
__global__ __launch_bounds__(256) void attn_kernel(const u16* __restrict__ Qb, int ldq, long qbs,
                                                   const u16* __restrict__ Kb, int ldk, long kbs,
                                                   const u16* __restrict__ Vb,
                                                   u16* __restrict__ Ob, int ldo, long obs,
                                                   int Sk, float scale) {
  __shared__ __align__(16) u16 Ks[64 * 104];   // [key][d pad 96->104]
  __shared__ __align__(16) u16 Vt[80 * 72];    // [d][key pad 64->72]
  __shared__ __align__(16) u16 Ps[4][16 * 72]; // per-wave P, [q][key pad]
  const short8 zero = {0, 0, 0, 0, 0, 0, 0, 0};
  const int tid = threadIdx.x;
  const int lane = tid & 63, w = tid >> 6;
  const int rq = lane & 15, g4 = lane >> 4;
  const int b = blockIdx.z, h = blockIdx.y;
  const u16* Q = Qb + (size_t)b * qbs + h * 80;
  const u16* Kp = Kb + (size_t)b * kbs + h * 80;
  const u16* Vp = Vb + (size_t)b * kbs + h * 80;
  u16* Op = Ob + (size_t)b * obs + h * 80;
  const int q0 = blockIdx.x * 64 + w * 16;

  short8 qa[3];
  for (int kk = 0; kk < 3; kk++) {
    int d = kk * 32 + g4 * 8;
    if (d < 80)
      qa[kk] = *(const short8*)(Q + (size_t)(q0 + rq) * ldq + d);
    else
      qa[kk] = zero;
  }
  f32x4 oacc[5] = {};
  float m_run[4], l_run[4];
  for (int r = 0; r < 4; r++) { m_run[r] = -1e30f; l_run[r] = 0.f; }

  const int nkt = (Sk + 63) >> 6;
  for (int kt = 0; kt < nkt; kt++) {
    // stage K tile [64][96] (zero-pad d>=80 and key>=Sk)
    for (int s = tid; s < 768; s += 256) {
      int row = s / 12, c = s % 12;
      int kidx = kt * 64 + row;
      short8 v = zero;
      if (c < 10 && kidx < Sk) v = *(const short8*)(Kp + (size_t)kidx * ldk + c * 8);
      *(short8*)&Ks[row * 104 + c * 8] = v;
    }
    // stage V^T [80][64]
    for (int s = tid; s < 640; s += 256) {
      int k = s & 63, c = s >> 6;
      int kidx = kt * 64 + k;
      short8 v = zero;
      if (kidx < Sk) v = *(const short8*)(Vp + (size_t)kidx * ldk + c * 8);
      for (int jj = 0; jj < 8; jj++) Vt[(c * 8 + jj) * 72 + k] = (u16)v[jj];
    }
    __syncthreads();

    // scores: 16 q x 64 k per wave
    f32x4 sc[4] = {};
    for (int n = 0; n < 4; n++)
      for (int kk = 0; kk < 3; kk++) {
        short8 kb = *(const short8*)&Ks[(n * 16 + rq) * 104 + kk * 32 + g4 * 8];
        sc[n] = __builtin_amdgcn_mfma_f32_16x16x32_bf16(qa[kk], kb, sc[n], 0, 0, 0);
      }
    int kbase = kt * 64;
    for (int n = 0; n < 4; n++) {
      sc[n] *= scale;
      if (kbase + n * 16 + rq >= Sk)
        for (int r = 0; r < 4; r++) sc[n][r] = -1e30f;
    }
    float tm[4];
    for (int r = 0; r < 4; r++)
      tm[r] = fmaxf(fmaxf(sc[0][r], sc[1][r]), fmaxf(sc[2][r], sc[3][r]));
    for (int off = 1; off < 16; off <<= 1)
      for (int r = 0; r < 4; r++) tm[r] = fmaxf(tm[r], __shfl_xor(tm[r], off));
    float sf[4], rs[4];
    for (int r = 0; r < 4; r++) {
      float mn = fmaxf(m_run[r], tm[r]);
      sf[r] = __expf(m_run[r] - mn);
      m_run[r] = mn;
      rs[r] = 0.f;
    }
    for (int n = 0; n < 4; n++)
      for (int r = 0; r < 4; r++) {
        float pv = __expf(sc[n][r] - m_run[r]);
        sc[n][r] = pv;
        rs[r] += pv;
      }
    for (int off = 1; off < 16; off <<= 1)
      for (int r = 0; r < 4; r++) rs[r] += __shfl_xor(rs[r], off);
    for (int r = 0; r < 4; r++) l_run[r] = l_run[r] * sf[r] + rs[r];
    for (int nn = 0; nn < 5; nn++)
      for (int r = 0; r < 4; r++) oacc[nn][r] *= sf[r];
    // P -> LDS (bf16), per-wave buffer
    for (int n = 0; n < 4; n++)
      for (int r = 0; r < 4; r++)
        Ps[w][(g4 * 4 + r) * 72 + n * 16 + rq] = f2bf(sc[n][r]);
    __syncthreads();
    // PV
    for (int s = 0; s < 2; s++) {
      short8 pa = *(const short8*)&Ps[w][rq * 72 + s * 32 + g4 * 8];
      for (int nn = 0; nn < 5; nn++) {
        short8 vb = *(const short8*)&Vt[(nn * 16 + rq) * 72 + s * 32 + g4 * 8];
        oacc[nn] = __builtin_amdgcn_mfma_f32_16x16x32_bf16(pa, vb, oacc[nn], 0, 0, 0);
      }
    }
    __syncthreads();
  }
  for (int nn = 0; nn < 5; nn++)
    for (int r = 0; r < 4; r++) {
      float v = oacc[nn][r] / l_run[r];
      Op[(size_t)(q0 + g4 * 4 + r) * ldo + nn * 16 + rq] = f2bf(v);
    }
}

extern "C" void kernel_launch(void* const* d_in, const int* in_sizes, int n_in,
                              void* d_out, int out_size, void* d_ws, size_t ws_size,
                              hipStream_t stream) {
  (void)in_sizes; (void)n_in; (void)out_size; (void)ws_size;
  const float* x = (const float*)d_in[0];
  const float* p = (const float*)d_in[1];
  const float* gn_g = (const float*)d_in[2];
  const float* gn_b = (const float*)d_in[3];
  const float* ci_w = (const float*)d_in[4];
  const float* ci_b = (const float*)d_in[5];
  const float* ln1_g = (const float*)d_in[6];
  const float* ln1_b = (const float*)d_in[7];
  const float* qkv_w = (const float*)d_in[8];
  const float* qkv_b = (const float*)d_in[9];
  const float* saw_w = (const float*)d_in[10];
  const float* saw_b = (const float*)d_in[11];
  const float* ln2_g = (const float*)d_in[12];
  const float* ln2_b = (const float*)d_in[13];
  const float* caq_w = (const float*)d_in[14];
  const float* caq_b = (const float*)d_in[15];
  const float* cak_w = (const float*)d_in[16];
  const float* cak_b = (const float*)d_in[17];
  const float* cav_w = (const float*)d_in[18];
  const float* cav_b = (const float*)d_in[19];
  const float* caw_w = (const float*)d_in[20];
  const float* caw_b = (const float*)d_in[21];
  const float* ln3_g = (const float*)d_in[22];
  const float* ln3_b = (const float*)d_in[23];
  const float* g1_w = (const float*)d_in[24];
  const float* g1_b = (const float*)d_in[25];
  const float* g2_w = (const float*)d_in[26];
  const float* g2_b = (const float*)d_in[27];
  const float* co_w = (const float*)d_in[28];
  const float* co_b = (const float*)d_in[29];
  float* out = (float*)d_out;

  char* ws = (char*)d_ws;
  size_t off = 0;
  auto alloc = [&](size_t bytes) {
    size_t o = off;
    off += (bytes + 255) & ~(size_t)255;
    return o;
  };
  u16* WCI = (u16*)(ws + alloc((size_t)640 * 640 * 2));
  u16* WQKV = (u16*)(ws + alloc((size_t)1920 * 640 * 2));
  u16* WSAW = (u16*)(ws + alloc((size_t)640 * 640 * 2));
  u16* WCAQ = (u16*)(ws + alloc((size_t)640 * 640 * 2));
  u16* WCAK = (u16*)(ws + alloc((size_t)640 * 512 * 2));
  u16* WCAV = (u16*)(ws + alloc((size_t)640 * 512 * 2));
  u16* WCAW = (u16*)(ws + alloc((size_t)640 * 640 * 2));
  u16* WG1 = (u16*)(ws + alloc((size_t)5120 * 640 * 2));
  u16* WG2 = (u16*)(ws + alloc((size_t)640 * 2560 * 2));
  u16* WCO = (u16*)(ws + alloc((size_t)640 * 640 * 2));
  u16* X = (u16*)(ws + alloc((size_t)8192 * 640 * 2));
  u16* Y = (u16*)(ws + alloc((size_t)8192 * 640 * 2));
  float* F1 = (float*)(ws + alloc((size_t)8192 * 640 * 4));
  u16* QKV = (u16*)(ws + alloc((size_t)8192 * 1920 * 2));
  u16* PBF = (u16*)(ws + alloc((size_t)616 * 512 * 2));
  u16* KC = (u16*)(ws + alloc((size_t)616 * 640 * 2));
  u16* VC = (u16*)(ws + alloc((size_t)616 * 640 * 2));
  u16* PROJ = (u16*)(ws + alloc((size_t)8192 * 5120 * 2));
  u16* TG = (u16*)(ws + alloc((size_t)8192 * 2560 * 2));
  float* GNM = (float*)(ws + alloc(256 * 4));
  float* GNR = (float*)(ws + alloc(256 * 4));

  // ---- weight prep (transpose to [N][K] bf16) ----
  prep_w<<<dim3(20, 20), 256, 0, stream>>>(ci_w, WCI, 640, 640);
  prep_w<<<dim3(60, 20), 256, 0, stream>>>(qkv_w, WQKV, 640, 1920);
  prep_w<<<dim3(20, 20), 256, 0, stream>>>(saw_w, WSAW, 640, 640);
  prep_w<<<dim3(20, 20), 256, 0, stream>>>(caq_w, WCAQ, 640, 640);
  prep_w<<<dim3(20, 16), 256, 0, stream>>>(cak_w, WCAK, 512, 640);
  prep_w<<<dim3(20, 16), 256, 0, stream>>>(cav_w, WCAV, 512, 640);
  prep_w<<<dim3(20, 20), 256, 0, stream>>>(caw_w, WCAW, 640, 640);
  prep_w<<<dim3(160, 20), 256, 0, stream>>>(g1_w, WG1, 640, 5120);
  prep_w<<<dim3(20, 80), 256, 0, stream>>>(g2_w, WG2, 2560, 640);
  prep_w<<<dim3(20, 20), 256, 0, stream>>>(co_w, WCO, 640, 640);
  conv_bf16<<<1232, 256, 0, stream>>>(p, PBF, (long)616 * 512);

  // ---- groupnorm + transpose to token-major bf16 ----
  gn_stats<<<256, 256, 0, stream>>>(x, GNM, GNR);
  gn_apply<<<dim3(32, 20, 8), 256, 0, stream>>>(x, GNM, GNR, gn_g, gn_b, X);

  const float scale = 0.11180339887498949f;  // 1/sqrt(80)

  // conv_input
  gemm_bt<0><<<dim3(64, 5), 256, 0, stream>>>(X, WCI, ci_b, F1, nullptr, 8192, 640, 640);
  // self-attention
  ln_kernel<<<2048, 256, 0, stream>>>(F1, ln1_g, ln1_b, Y);
  gemm_bt<1><<<dim3(64, 15), 256, 0, stream>>>(Y, WQKV, qkv_b, QKV, nullptr, 8192, 1920, 640);
  attn_kernel<<<dim3(16, 8, 8), 256, 0, stream>>>(QKV, 1920, (long)1024 * 1920,
                                                  QKV + 640, 1920, (long)1024 * 1920,
                                                  QKV + 1280, X, 640, (long)1024 * 640,
                                                  1024, scale);
  gemm_bt<2><<<dim3(64, 5), 256, 0, stream>>>(X, WSAW, saw_b, F1, F1, 8192, 640, 640);
  // cross-attention
  ln_kernel<<<2048, 256, 0, stream>>>(F1, ln2_g, ln2_b, Y);
  gemm_bt<1><<<dim3(64, 5), 256, 0, stream>>>(Y, WCAQ, caq_b, X, nullptr, 8192, 640, 640);
  gemm_bt<1><<<dim3(5, 5), 256, 0, stream>>>(PBF, WCAK, cak_b, KC, nullptr, 616, 640, 512);
  gemm_bt<1><<<dim3(5, 5), 256, 0, stream>>>(PBF, WCAV, cav_b, VC, nullptr, 616, 640, 512);
  attn_kernel<<<dim3(16, 8, 8), 256, 0, stream>>>(X, 640, (long)1024 * 640,
                                                  KC, 640, (long)77 * 640,
                                                  VC, Y, 640, (long)1024 * 640,
                                                  77, scale);
  gemm_bt<2><<<dim3(64, 5), 256, 0, stream>>>(Y, WCAW, caw_b, F1, F1, 8192, 640, 640);
  // GEGLU MLP
  ln_kernel<<<2048, 256, 0, stream>>>(F1, ln3_g, ln3_b, X);
  gemm_bt<1><<<dim3(64, 40), 256, 0, stream>>>(X, WG1, g1_b, PROJ, nullptr, 8192, 5120, 640);
  geglu<<<10240, 256, 0, stream>>>(PROJ, TG);
  gemm_bt<2><<<dim3(64, 5), 256, 0, stream>>>(TG, WG2, g2_b, F1, F1, 8192, 640, 2560);
  // conv_output + long residual (transposed store)
  conv_bf16<<<20480, 256, 0, stream>>>(F1, X, (long)8192 * 640);
  gemm_bt<3><<<dim3(64, 5), 256, 0, stream>>>(X, WCO, co_b, out, x, 8192, 640, 640);
}

// Round 3
// 582.012 us; speedup vs baseline: 1.1260x; 1.1260x over previous
//
#include <hip/hip_runtime.h>
#include <math.h>

typedef unsigned short u16;
typedef __attribute__((ext_vector_type(8))) short short8;
typedef __attribute__((ext_vector_type(4))) float f32x4;

#define DI static __device__ __forceinline__

DI float bf2f(u16 u) { union { unsigned u; float f; } c; c.u = (unsigned)u << 16; return c.f; }
DI u16 f2bf(float f) {
  union { float f; unsigned u; } c; c.f = f;
  unsigned r = c.u + 0x7fffu + ((c.u >> 16) & 1u);
  return (u16)(r >> 16);
}

// async global->LDS, 16 bytes per lane; dest MUST be wave-linear (base + lane*16)
DI void gload16(const u16* g, u16* l) {
  __builtin_amdgcn_global_load_lds(
      (const __attribute__((address_space(1))) unsigned int*)g,
      (__attribute__((address_space(3))) unsigned int*)l, 16, 0, 0);
}

// ---------- weight prep: w[K][N] f32 -> wt[N][K] bf16 (transpose + convert) ----------
__global__ __launch_bounds__(256) void prep_w(const float* __restrict__ w,
                                              u16* __restrict__ wt, int K, int N) {
  __shared__ float tile[32][33];
  int k0 = blockIdx.y * 32, n0 = blockIdx.x * 32;
  int tid = threadIdx.x;
  int ni = tid & 31, ki8 = tid >> 5;
  for (int i = 0; i < 4; i++) {
    int k = ki8 + i * 8;
    tile[k][ni] = w[(size_t)(k0 + k) * N + n0 + ni];
  }
  __syncthreads();
  int kj = tid & 31, nj8 = tid >> 5;
  for (int i = 0; i < 4; i++) {
    int n = nj8 + i * 8;
    wt[(size_t)(n0 + n) * K + k0 + kj] = f2bf(tile[kj][n]);
  }
}

// ---------- generic f32 -> bf16 ----------
__global__ __launch_bounds__(256) void conv_bf16(const float* __restrict__ in,
                                                 u16* __restrict__ out, long n) {
  long i = (long)blockIdx.x * 256 + threadIdx.x;
  if (i < n) out[i] = f2bf(in[i]);
}

// ---------- GroupNorm stats: one block per (b,g), 20*1024 elems ----------
__global__ __launch_bounds__(256) void gn_stats(const float* __restrict__ x,
                                                float* __restrict__ mean_o,
                                                float* __restrict__ rstd_o) {
  int bg = blockIdx.x;
  const float4* p = (const float4*)(x + (size_t)bg * 20480);
  float s = 0.f, sq = 0.f;
  for (int i = threadIdx.x; i < 5120; i += 256) {
    float4 v = p[i];
    s += v.x + v.y + v.z + v.w;
    sq += v.x * v.x + v.y * v.y + v.z * v.z + v.w * v.w;
  }
  for (int off = 1; off < 64; off <<= 1) { s += __shfl_xor(s, off); sq += __shfl_xor(sq, off); }
  __shared__ float ps[4], pq[4];
  int w = threadIdx.x >> 6;
  if ((threadIdx.x & 63) == 0) { ps[w] = s; pq[w] = sq; }
  __syncthreads();
  if (threadIdx.x == 0) {
    float S = ps[0] + ps[1] + ps[2] + ps[3];
    float Q = pq[0] + pq[1] + pq[2] + pq[3];
    float mu = S / 20480.f;
    float var = Q / 20480.f - mu * mu;
    mean_o[bg] = mu;
    rstd_o[bg] = rsqrtf(var + 1e-5f);
  }
}

// ---------- GN apply + transpose (B,C,S) -> bf16 (B*S, C) ----------
__global__ __launch_bounds__(256) void gn_apply(const float* __restrict__ x,
                                                const float* __restrict__ mean_,
                                                const float* __restrict__ rstd_,
                                                const float* __restrict__ g,
                                                const float* __restrict__ bb,
                                                u16* __restrict__ out) {
  __shared__ float tile[32][33];
  int b = blockIdx.z, c0 = blockIdx.y * 32, s0 = blockIdx.x * 32;
  int tid = threadIdx.x;
  int si = tid & 31, ci8 = tid >> 5;
  for (int i = 0; i < 4; i++) {
    int c = c0 + ci8 + i * 8;
    int gg = c / 20;
    float mu = mean_[b * 32 + gg], rs = rstd_[b * 32 + gg];
    float v = x[((size_t)b * 640 + c) * 1024 + s0 + si];
    tile[ci8 + i * 8][si] = (v - mu) * rs * g[c] + bb[c];
  }
  __syncthreads();
  int cj = tid & 31, sj8 = tid >> 5;
  for (int i = 0; i < 4; i++) {
    int sj = sj8 + i * 8;
    out[((size_t)b * 1024 + s0 + sj) * 640 + c0 + cj] = f2bf(tile[cj][sj]);
  }
}

// ---------- LayerNorm: fp32 [T,640] -> bf16 [T,640]; one wave per token ----------
__global__ __launch_bounds__(256) void ln_kernel(const float* __restrict__ in,
                                                 const float* __restrict__ g,
                                                 const float* __restrict__ bb,
                                                 u16* __restrict__ out) {
  int t = blockIdx.x * 4 + (threadIdx.x >> 6);
  int lane = threadIdx.x & 63;
  const float* row = in + (size_t)t * 640;
  float xv[10], s = 0.f, sq = 0.f;
  for (int j = 0; j < 10; j++) {
    xv[j] = row[lane + j * 64];
    s += xv[j];
    sq += xv[j] * xv[j];
  }
  for (int off = 1; off < 64; off <<= 1) { s += __shfl_xor(s, off); sq += __shfl_xor(sq, off); }
  float mu = s * (1.f / 640.f);
  float var = sq * (1.f / 640.f) - mu * mu;
  float rstd = rsqrtf(var + 1e-5f);
  for (int j = 0; j < 10; j++) {
    int c = lane + j * 64;
    out[(size_t)t * 640 + c] = f2bf((xv[j] - mu) * rstd * g[c] + bb[c]);
  }
}

// ---------- GEGLU: proj bf16 [T,5120] -> tg bf16 [T,2560] ----------
__global__ __launch_bounds__(256) void geglu(const u16* __restrict__ proj,
                                             u16* __restrict__ tg) {
  long i = (long)blockIdx.x * 256 + threadIdx.x;
  int t = (int)(i / 320);
  int j8 = (int)(i % 320) * 8;
  short8 av = *(const short8*)(proj + (size_t)t * 5120 + j8);
  short8 gv = *(const short8*)(proj + (size_t)t * 5120 + 2560 + j8);
  short8 o;
  for (int r = 0; r < 8; r++) {
    float a = bf2f((u16)av[r]);
    float gx = bf2f((u16)gv[r]);
    float gl = 0.5f * gx * (1.f + erff(gx * 0.70710678f));
    o[r] = (short)f2bf(a * gl);
  }
  *(short8*)(tg + (size_t)t * 2560 + j8) = o;
}

// ---------- GEMM: C[M,N] = A[M,K](bf16) x Bt[N,K](bf16)^T + bias ----------
// m97 structure: 128x128 tile, BK=32, linear LDS, global_load_lds width-16 staging.
// MODE 0: out fp32       MODE 1: out bf16
// MODE 2: out fp32 = acc + bias + res (in-place residual ok)
// MODE 3: final: out fp32 [B,640,1024] at (b,n,s) = acc + bias + x[b,n,s]
template <int MODE>
__global__ __launch_bounds__(256) void gemm_bt(const u16* __restrict__ A,
                                               const u16* __restrict__ Bt,
                                               const float* __restrict__ bias,
                                               void* outp, const float* res,
                                               int M, int N, int K) {
  __shared__ __align__(16) u16 As[128 * 32];
  __shared__ __align__(16) u16 Bs[128 * 32];
  const int tid = threadIdx.x;
  const int lane = tid & 63, wid = tid >> 6;
  const int wm = wid >> 1, wn = wid & 1;
  const int m0 = blockIdx.x * 128, n0 = blockIdx.y * 128;
  const int rq = lane & 15, g4 = lane >> 4;

  // staging map: each thread owns one 16B chunk; dest is wave-linear (base+lane*16)
  const int srow = tid >> 2;   // 0..63
  const int scol = tid & 3;    // which 16B chunk of the 64B row (BK=32 bf16)
  int gmA0 = m0 + srow;        if (gmA0 >= M) gmA0 = M - 1;
  int gmA1 = m0 + 64 + srow;   if (gmA1 >= M) gmA1 = M - 1;
  const u16* gA0 = A + (size_t)gmA0 * K + scol * 8;
  const u16* gA1 = A + (size_t)gmA1 * K + scol * 8;
  const u16* gB0 = Bt + (size_t)(n0 + srow) * K + scol * 8;
  const u16* gB1 = Bt + (size_t)(n0 + 64 + srow) * K + scol * 8;
  u16* lA0 = As + srow * 32 + scol * 8;
  u16* lA1 = As + (64 + srow) * 32 + scol * 8;
  u16* lB0 = Bs + srow * 32 + scol * 8;
  u16* lB1 = Bs + (64 + srow) * 32 + scol * 8;

  f32x4 acc[4][4] = {};

  for (int k0 = 0; k0 < K; k0 += 32) {
    gload16(gA0 + k0, lA0);
    gload16(gA1 + k0, lA1);
    gload16(gB0 + k0, lB0);
    gload16(gB1 + k0, lB1);
    __syncthreads();
    short8 af[4], bfr[4];
    for (int i = 0; i < 4; i++)
      af[i] = *(const short8*)&As[(wm * 64 + i * 16 + rq) * 32 + g4 * 8];
    for (int j = 0; j < 4; j++)
      bfr[j] = *(const short8*)&Bs[(wn * 64 + j * 16 + rq) * 32 + g4 * 8];
    for (int i = 0; i < 4; i++)
      for (int j = 0; j < 4; j++)
        acc[i][j] = __builtin_amdgcn_mfma_f32_16x16x32_bf16(af[i], bfr[j], acc[i][j], 0, 0, 0);
    __syncthreads();
  }

  for (int j = 0; j < 4; j++) {
    int n = n0 + wn * 64 + j * 16 + rq;
    float bv = bias[n];
    for (int i = 0; i < 4; i++) {
      int mb = m0 + wm * 64 + i * 16 + g4 * 4;
      f32x4 v = acc[i][j];
      if (MODE == 3) {
        int b = mb >> 10, sp = mb & 1023;
        size_t off = ((size_t)b * 640 + n) * 1024 + sp;
        f32x4 xv = *(const f32x4*)(res + off);
        f32x4 o;
        for (int r = 0; r < 4; r++) o[r] = v[r] + bv + xv[r];
        *(f32x4*)((float*)outp + off) = o;
      } else {
        for (int r = 0; r < 4; r++) {
          int m = mb + r;
          if (m >= M) break;
          size_t off = (size_t)m * N + n;
          float val = v[r] + bv;
          if (MODE == 0)
            ((float*)outp)[off] = val;
          else if (MODE == 1)
            ((u16*)outp)[off] = f2bf(val);
          else
            ((float*)outp)[off] = val + res[off];
        }
      }
    }
  }
}

// ---------- flash attention: HD=80 (padded 96), 64 queries/block, 4 waves ----------
__global__ __launch_bounds__(256) void attn_kernel(const u16* __restrict__ Qb, int ldq, long qbs,
                                                   const u16* __restrict__ Kb, int ldk, long kbs,
                                                   const u16* __restrict__ Vb,
                                                   u16* __restrict__ Ob, int ldo, long obs,
                                                   int Sk, float scale) {
  __shared__ __align__(16) u16 Ks[64 * 104];   // [key][d pad 96->104]
  __shared__ __align__(16) u16 Vt[80 * 72];    // [d][key pad 64->72]
  __shared__ __align__(16) u16 Ps[4][16 * 72]; // per-wave P, [q][key pad]
  const short8 zero = {0, 0, 0, 0, 0, 0, 0, 0};
  const int tid = threadIdx.x;
  const int lane = tid & 63, w = tid >> 6;
  const int rq = lane & 15, g4 = lane >> 4;
  const int b = blockIdx.z, h = blockIdx.y;
  const u16* Q = Qb + (size_t)b * qbs + h * 80;
  const u16* Kp = Kb + (size_t)b * kbs + h * 80;
  const u16* Vp = Vb + (size_t)b * kbs + h * 80;
  u16* Op = Ob + (size_t)b * obs + h * 80;
  const int q0 = blockIdx.x * 64 + w * 16;

  short8 qa[3];
  for (int kk = 0; kk < 3; kk++) {
    int d = kk * 32 + g4 * 8;
    if (d < 80)
      qa[kk] = *(const short8*)(Q + (size_t)(q0 + rq) * ldq + d);
    else
      qa[kk] = zero;
  }
  f32x4 oacc[5] = {};
  float m_run[4], l_run[4];
  for (int r = 0; r < 4; r++) { m_run[r] = -1e30f; l_run[r] = 0.f; }

  const int nkt = (Sk + 63) >> 6;
  for (int kt = 0; kt < nkt; kt++) {
    // stage K tile [64][96] (zero-pad d>=80 and key>=Sk)
    for (int s = tid; s < 768; s += 256) {
      int row = s / 12, c = s % 12;
      int kidx = kt * 64 + row;
      short8 v = zero;
      if (c < 10 && kidx < Sk) v = *(const short8*)(Kp + (size_t)kidx * ldk + c * 8);
      *(short8*)&Ks[row * 104 + c * 8] = v;
    }
    // stage V^T [80][64]
    for (int s = tid; s < 640; s += 256) {
      int k = s & 63, c = s >> 6;
      int kidx = kt * 64 + k;
      short8 v = zero;
      if (kidx < Sk) v = *(const short8*)(Vp + (size_t)kidx * ldk + c * 8);
      for (int jj = 0; jj < 8; jj++) Vt[(c * 8 + jj) * 72 + k] = (u16)v[jj];
    }
    __syncthreads();

    // scores: 16 q x 64 k per wave
    f32x4 sc[4] = {};
    for (int n = 0; n < 4; n++)
      for (int kk = 0; kk < 3; kk++) {
        short8 kb = *(const short8*)&Ks[(n * 16 + rq) * 104 + kk * 32 + g4 * 8];
        sc[n] = __builtin_amdgcn_mfma_f32_16x16x32_bf16(qa[kk], kb, sc[n], 0, 0, 0);
      }
    int kbase = kt * 64;
    for (int n = 0; n < 4; n++) {
      sc[n] *= scale;
      if (kbase + n * 16 + rq >= Sk)
        for (int r = 0; r < 4; r++) sc[n][r] = -1e30f;
    }
    float tm[4];
    for (int r = 0; r < 4; r++)
      tm[r] = fmaxf(fmaxf(sc[0][r], sc[1][r]), fmaxf(sc[2][r], sc[3][r]));
    for (int off = 1; off < 16; off <<= 1)
      for (int r = 0; r < 4; r++) tm[r] = fmaxf(tm[r], __shfl_xor(tm[r], off));
    float sf[4], rs[4];
    for (int r = 0; r < 4; r++) {
      float mn = fmaxf(m_run[r], tm[r]);
      sf[r] = __expf(m_run[r] - mn);
      m_run[r] = mn;
      rs[r] = 0.f;
    }
    for (int n = 0; n < 4; n++)
      for (int r = 0; r < 4; r++) {
        float pv = __expf(sc[n][r] - m_run[r]);
        sc[n][r] = pv;
        rs[r] += pv;
      }
    for (int off = 1; off < 16; off <<= 1)
      for (int r = 0; r < 4; r++) rs[r] += __shfl_xor(rs[r], off);
    for (int r = 0; r < 4; r++) l_run[r] = l_run[r] * sf[r] + rs[r];
    for (int nn = 0; nn < 5; nn++)
      for (int r = 0; r < 4; r++) oacc[nn][r] *= sf[r];
    // P -> LDS (bf16), per-wave buffer
    for (int n = 0; n < 4; n++)
      for (int r = 0; r < 4; r++)
        Ps[w][(g4 * 4 + r) * 72 + n * 16 + rq] = f2bf(sc[n][r]);
    __syncthreads();
    // PV
    for (int s = 0; s < 2; s++) {
      short8 pa = *(const short8*)&Ps[w][rq * 72 + s * 32 + g4 * 8];
      for (int nn = 0; nn < 5; nn++) {
        short8 vb = *(const short8*)&Vt[(nn * 16 + rq) * 72 + s * 32 + g4 * 8];
        oacc[nn] = __builtin_amdgcn_mfma_f32_16x16x32_bf16(pa, vb, oacc[nn], 0, 0, 0);
      }
    }
    __syncthreads();
  }
  for (int nn = 0; nn < 5; nn++)
    for (int r = 0; r < 4; r++) {
      float v = oacc[nn][r] / l_run[r];
      Op[(size_t)(q0 + g4 * 4 + r) * ldo + nn * 16 + rq] = f2bf(v);
    }
}

extern "C" void kernel_launch(void* const* d_in, const int* in_sizes, int n_in,
                              void* d_out, int out_size, void* d_ws, size_t ws_size,
                              hipStream_t stream) {
  (void)in_sizes; (void)n_in; (void)out_size; (void)ws_size;
  const float* x = (const float*)d_in[0];
  const float* p = (const float*)d_in[1];
  const float* gn_g = (const float*)d_in[2];
  const float* gn_b = (const float*)d_in[3];
  const float* ci_w = (const float*)d_in[4];
  const float* ci_b = (const float*)d_in[5];
  const float* ln1_g = (const float*)d_in[6];
  const float* ln1_b = (const float*)d_in[7];
  const float* qkv_w = (const float*)d_in[8];
  const float* qkv_b = (const float*)d_in[9];
  const float* saw_w = (const float*)d_in[10];
  const float* saw_b = (const float*)d_in[11];
  const float* ln2_g = (const float*)d_in[12];
  const float* ln2_b = (const float*)d_in[13];
  const float* caq_w = (const float*)d_in[14];
  const float* caq_b = (const float*)d_in[15];
  const float* cak_w = (const float*)d_in[16];
  const float* cak_b = (const float*)d_in[17];
  const float* cav_w = (const float*)d_in[18];
  const float* cav_b = (const float*)d_in[19];
  const float* caw_w = (const float*)d_in[20];
  const float* caw_b = (const float*)d_in[21];
  const float* ln3_g = (const float*)d_in[22];
  const float* ln3_b = (const float*)d_in[23];
  const float* g1_w = (const float*)d_in[24];
  const float* g1_b = (const float*)d_in[25];
  const float* g2_w = (const float*)d_in[26];
  const float* g2_b = (const float*)d_in[27];
  const float* co_w = (const float*)d_in[28];
  const float* co_b = (const float*)d_in[29];
  float* out = (float*)d_out;

  char* ws = (char*)d_ws;
  size_t off = 0;
  auto alloc = [&](size_t bytes) {
    size_t o = off;
    off += (bytes + 255) & ~(size_t)255;
    return o;
  };
  u16* WCI = (u16*)(ws + alloc((size_t)640 * 640 * 2));
  u16* WQKV = (u16*)(ws + alloc((size_t)1920 * 640 * 2));
  u16* WSAW = (u16*)(ws + alloc((size_t)640 * 640 * 2));
  u16* WCAQ = (u16*)(ws + alloc((size_t)640 * 640 * 2));
  u16* WCAK = (u16*)(ws + alloc((size_t)640 * 512 * 2));
  u16* WCAV = (u16*)(ws + alloc((size_t)640 * 512 * 2));
  u16* WCAW = (u16*)(ws + alloc((size_t)640 * 640 * 2));
  u16* WG1 = (u16*)(ws + alloc((size_t)5120 * 640 * 2));
  u16* WG2 = (u16*)(ws + alloc((size_t)640 * 2560 * 2));
  u16* WCO = (u16*)(ws + alloc((size_t)640 * 640 * 2));
  u16* X = (u16*)(ws + alloc((size_t)8192 * 640 * 2));
  u16* Y = (u16*)(ws + alloc((size_t)8192 * 640 * 2));
  float* F1 = (float*)(ws + alloc((size_t)8192 * 640 * 4));
  u16* QKV = (u16*)(ws + alloc((size_t)8192 * 1920 * 2));
  u16* PBF = (u16*)(ws + alloc((size_t)616 * 512 * 2));
  u16* KC = (u16*)(ws + alloc((size_t)616 * 640 * 2));
  u16* VC = (u16*)(ws + alloc((size_t)616 * 640 * 2));
  u16* PROJ = (u16*)(ws + alloc((size_t)8192 * 5120 * 2));
  u16* TG = (u16*)(ws + alloc((size_t)8192 * 2560 * 2));
  float* GNM = (float*)(ws + alloc(256 * 4));
  float* GNR = (float*)(ws + alloc(256 * 4));

  // ---- weight prep (transpose to [N][K] bf16) ----
  prep_w<<<dim3(20, 20), 256, 0, stream>>>(ci_w, WCI, 640, 640);
  prep_w<<<dim3(60, 20), 256, 0, stream>>>(qkv_w, WQKV, 640, 1920);
  prep_w<<<dim3(20, 20), 256, 0, stream>>>(saw_w, WSAW, 640, 640);
  prep_w<<<dim3(20, 20), 256, 0, stream>>>(caq_w, WCAQ, 640, 640);
  prep_w<<<dim3(20, 16), 256, 0, stream>>>(cak_w, WCAK, 512, 640);
  prep_w<<<dim3(20, 16), 256, 0, stream>>>(cav_w, WCAV, 512, 640);
  prep_w<<<dim3(20, 20), 256, 0, stream>>>(caw_w, WCAW, 640, 640);
  prep_w<<<dim3(160, 20), 256, 0, stream>>>(g1_w, WG1, 640, 5120);
  prep_w<<<dim3(20, 80), 256, 0, stream>>>(g2_w, WG2, 2560, 640);
  prep_w<<<dim3(20, 20), 256, 0, stream>>>(co_w, WCO, 640, 640);
  conv_bf16<<<1232, 256, 0, stream>>>(p, PBF, (long)616 * 512);

  // ---- groupnorm + transpose to token-major bf16 ----
  gn_stats<<<256, 256, 0, stream>>>(x, GNM, GNR);
  gn_apply<<<dim3(32, 20, 8), 256, 0, stream>>>(x, GNM, GNR, gn_g, gn_b, X);

  const float scale = 0.11180339887498949f;  // 1/sqrt(80)

  // conv_input
  gemm_bt<0><<<dim3(64, 5), 256, 0, stream>>>(X, WCI, ci_b, F1, nullptr, 8192, 640, 640);
  // self-attention
  ln_kernel<<<2048, 256, 0, stream>>>(F1, ln1_g, ln1_b, Y);
  gemm_bt<1><<<dim3(64, 15), 256, 0, stream>>>(Y, WQKV, qkv_b, QKV, nullptr, 8192, 1920, 640);
  attn_kernel<<<dim3(16, 8, 8), 256, 0, stream>>>(QKV, 1920, (long)1024 * 1920,
                                                  QKV + 640, 1920, (long)1024 * 1920,
                                                  QKV + 1280, X, 640, (long)1024 * 640,
                                                  1024, scale);
  gemm_bt<2><<<dim3(64, 5), 256, 0, stream>>>(X, WSAW, saw_b, F1, F1, 8192, 640, 640);
  // cross-attention
  ln_kernel<<<2048, 256, 0, stream>>>(F1, ln2_g, ln2_b, Y);
  gemm_bt<1><<<dim3(64, 5), 256, 0, stream>>>(Y, WCAQ, caq_b, X, nullptr, 8192, 640, 640);
  gemm_bt<1><<<dim3(5, 5), 256, 0, stream>>>(PBF, WCAK, cak_b, KC, nullptr, 616, 640, 512);
  gemm_bt<1><<<dim3(5, 5), 256, 0, stream>>>(PBF, WCAV, cav_b, VC, nullptr, 616, 640, 512);
  attn_kernel<<<dim3(16, 8, 8), 256, 0, stream>>>(X, 640, (long)1024 * 640,
                                                  KC, 640, (long)77 * 640,
                                                  VC, Y, 640, (long)1024 * 640,
                                                  77, scale);
  gemm_bt<2><<<dim3(64, 5), 256, 0, stream>>>(Y, WCAW, caw_b, F1, F1, 8192, 640, 640);
  // GEGLU MLP
  ln_kernel<<<2048, 256, 0, stream>>>(F1, ln3_g, ln3_b, X);
  gemm_bt<1><<<dim3(64, 40), 256, 0, stream>>>(X, WG1, g1_b, PROJ, nullptr, 8192, 5120, 640);
  geglu<<<10240, 256, 0, stream>>>(PROJ, TG);
  gemm_bt<2><<<dim3(64, 5), 256, 0, stream>>>(TG, WG2, g2_b, F1, F1, 8192, 640, 2560);
  // conv_output + long residual (transposed store)
  conv_bf16<<<20480, 256, 0, stream>>>(F1, X, (long)8192 * 640);
  gemm_bt<3><<<dim3(64, 5), 256, 0, stream>>>(X, WCO, co_b, out, x, 8192, 640, 640);
}

// Round 4
// 549.821 us; speedup vs baseline: 1.1919x; 1.0585x over previous
//
#include <hip/hip_runtime.h>
#include <math.h>

typedef unsigned short u16;
typedef __attribute__((ext_vector_type(8))) short short8;
typedef __attribute__((ext_vector_type(4))) float f32x4;

#define DI static __device__ __forceinline__

DI float bf2f(u16 u) { union { unsigned u; float f; } c; c.u = (unsigned)u << 16; return c.f; }
DI u16 f2bf(float f) {
  union { float f; unsigned u; } c; c.f = f;
  unsigned r = c.u + 0x7fffu + ((c.u >> 16) & 1u);
  return (u16)(r >> 16);
}

// async global->LDS, 16 bytes per lane; dest MUST be wave-linear (base + lane*16)
DI void gload16(const u16* g, u16* l) {
  __builtin_amdgcn_global_load_lds(
      (const __attribute__((address_space(1))) unsigned int*)g,
      (__attribute__((address_space(3))) unsigned int*)l, 16, 0, 0);
}

// ---------- merged weight prep: 10 transposes in one dispatch ----------
struct PrepDesc { const float* src; u16* dst; int K, N, nbx, boff; };
struct PrepArgs { PrepDesc d[10]; };

__global__ __launch_bounds__(256) void prep_all(PrepArgs a) {
  int bid = blockIdx.x;
  int i = 0;
  while (i < 9 && bid >= a.d[i + 1].boff) i++;
  const PrepDesc D = a.d[i];
  int rel = bid - D.boff;
  int bx = rel % D.nbx, by = rel / D.nbx;
  int K = D.K, N = D.N;
  __shared__ float tile[32][33];
  int k0 = by * 32, n0 = bx * 32;
  int tid = threadIdx.x;
  int ni = tid & 31, ki8 = tid >> 5;
  for (int q = 0; q < 4; q++) {
    int k = ki8 + q * 8;
    tile[k][ni] = D.src[(size_t)(k0 + k) * N + n0 + ni];
  }
  __syncthreads();
  int kj = tid & 31, nj8 = tid >> 5;
  for (int q = 0; q < 4; q++) {
    int n = nj8 + q * 8;
    D.dst[(size_t)(n0 + n) * K + k0 + kj] = f2bf(tile[kj][n]);
  }
}

// ---------- generic f32 -> bf16 ----------
__global__ __launch_bounds__(256) void conv_bf16(const float* __restrict__ in,
                                                 u16* __restrict__ out, long n) {
  long i = (long)blockIdx.x * 256 + threadIdx.x;
  if (i < n) out[i] = f2bf(in[i]);
}

// ---------- GroupNorm stats: one block per (b,g), 20*1024 elems ----------
__global__ __launch_bounds__(256) void gn_stats(const float* __restrict__ x,
                                                float* __restrict__ mean_o,
                                                float* __restrict__ rstd_o) {
  int bg = blockIdx.x;
  const float4* p = (const float4*)(x + (size_t)bg * 20480);
  float s = 0.f, sq = 0.f;
  for (int i = threadIdx.x; i < 5120; i += 256) {
    float4 v = p[i];
    s += v.x + v.y + v.z + v.w;
    sq += v.x * v.x + v.y * v.y + v.z * v.z + v.w * v.w;
  }
  for (int off = 1; off < 64; off <<= 1) { s += __shfl_xor(s, off); sq += __shfl_xor(sq, off); }
  __shared__ float ps[4], pq[4];
  int w = threadIdx.x >> 6;
  if ((threadIdx.x & 63) == 0) { ps[w] = s; pq[w] = sq; }
  __syncthreads();
  if (threadIdx.x == 0) {
    float S = ps[0] + ps[1] + ps[2] + ps[3];
    float Q = pq[0] + pq[1] + pq[2] + pq[3];
    float mu = S / 20480.f;
    float var = Q / 20480.f - mu * mu;
    mean_o[bg] = mu;
    rstd_o[bg] = rsqrtf(var + 1e-5f);
  }
}

// ---------- GN apply + transpose (B,C,S) -> bf16 (B*S, C) ----------
__global__ __launch_bounds__(256) void gn_apply(const float* __restrict__ x,
                                                const float* __restrict__ mean_,
                                                const float* __restrict__ rstd_,
                                                const float* __restrict__ g,
                                                const float* __restrict__ bb,
                                                u16* __restrict__ out) {
  __shared__ float tile[32][33];
  int b = blockIdx.z, c0 = blockIdx.y * 32, s0 = blockIdx.x * 32;
  int tid = threadIdx.x;
  int si = tid & 31, ci8 = tid >> 5;
  for (int i = 0; i < 4; i++) {
    int c = c0 + ci8 + i * 8;
    int gg = c / 20;
    float mu = mean_[b * 32 + gg], rs = rstd_[b * 32 + gg];
    float v = x[((size_t)b * 640 + c) * 1024 + s0 + si];
    tile[ci8 + i * 8][si] = (v - mu) * rs * g[c] + bb[c];
  }
  __syncthreads();
  int cj = tid & 31, sj8 = tid >> 5;
  for (int i = 0; i < 4; i++) {
    int sj = sj8 + i * 8;
    out[((size_t)b * 1024 + s0 + sj) * 640 + c0 + cj] = f2bf(tile[cj][sj]);
  }
}

// ---------- LayerNorm: fp32 [T,640] -> bf16 [T,640]; one wave per token ----------
__global__ __launch_bounds__(256) void ln_kernel(const float* __restrict__ in,
                                                 const float* __restrict__ g,
                                                 const float* __restrict__ bb,
                                                 u16* __restrict__ out) {
  int t = blockIdx.x * 4 + (threadIdx.x >> 6);
  int lane = threadIdx.x & 63;
  const float* row = in + (size_t)t * 640;
  float xv[10], s = 0.f, sq = 0.f;
  for (int j = 0; j < 10; j++) {
    xv[j] = row[lane + j * 64];
    s += xv[j];
    sq += xv[j] * xv[j];
  }
  for (int off = 1; off < 64; off <<= 1) { s += __shfl_xor(s, off); sq += __shfl_xor(sq, off); }
  float mu = s * (1.f / 640.f);
  float var = sq * (1.f / 640.f) - mu * mu;
  float rstd = rsqrtf(var + 1e-5f);
  for (int j = 0; j < 10; j++) {
    int c = lane + j * 64;
    out[(size_t)t * 640 + c] = f2bf((xv[j] - mu) * rstd * g[c] + bb[c]);
  }
}

// ---------- GEGLU: proj bf16 [T,5120] -> tg bf16 [T,2560] ----------
__global__ __launch_bounds__(256) void geglu(const u16* __restrict__ proj,
                                             u16* __restrict__ tg) {
  long i = (long)blockIdx.x * 256 + threadIdx.x;
  int t = (int)(i / 320);
  int j8 = (int)(i % 320) * 8;
  short8 av = *(const short8*)(proj + (size_t)t * 5120 + j8);
  short8 gv = *(const short8*)(proj + (size_t)t * 5120 + 2560 + j8);
  short8 o;
  for (int r = 0; r < 8; r++) {
    float a = bf2f((u16)av[r]);
    float gx = bf2f((u16)gv[r]);
    float gl = 0.5f * gx * (1.f + erff(gx * 0.70710678f));
    o[r] = (short)f2bf(a * gl);
  }
  *(short8*)(tg + (size_t)t * 2560 + j8) = o;
}

// ---------- GEMM: C[M,N] = A[M,K](bf16) x Bt[N,K](bf16)^T + bias ----------
// 128x128 tile, BK=32, linear LDS, global_load_lds staging, 2-phase double-buffer
// with counted vmcnt + raw barriers (T3-min/T4) and setprio around MFMA (T5).
// MODE 0: out fp32       MODE 1: out bf16
// MODE 2: out fp32 = acc + bias + res (in-place residual ok)
// MODE 3: final: out fp32 [B,640,1024] at (b,n,s) = acc + bias + x[b,n,s]
// MODE 4: out bf16 = acc + bias + res(fp32)
template <int MODE>
__global__ __launch_bounds__(256) void gemm_bt(const u16* __restrict__ A,
                                               const u16* __restrict__ Bt,
                                               const float* __restrict__ bias,
                                               void* outp, const float* res,
                                               int M, int N, int K) {
  __shared__ __align__(16) u16 As[2][128 * 32];
  __shared__ __align__(16) u16 Bs[2][128 * 32];
  const int tid = threadIdx.x;
  const int lane = tid & 63, wid = tid >> 6;
  const int wm = wid >> 1, wn = wid & 1;
  const int m0 = blockIdx.x * 128, n0 = blockIdx.y * 128;
  const int rq = lane & 15, g4 = lane >> 4;

  // staging map: each thread owns one 16B chunk; dest is wave-linear (base+lane*16)
  const int srow = tid >> 2;   // 0..63
  const int scol = tid & 3;    // which 16B chunk of the 64B row (BK=32 bf16)
  int gmA0 = m0 + srow;        if (gmA0 >= M) gmA0 = M - 1;
  int gmA1 = m0 + 64 + srow;   if (gmA1 >= M) gmA1 = M - 1;
  const u16* gA0 = A + (size_t)gmA0 * K + scol * 8;
  const u16* gA1 = A + (size_t)gmA1 * K + scol * 8;
  const u16* gB0 = Bt + (size_t)(n0 + srow) * K + scol * 8;
  const u16* gB1 = Bt + (size_t)(n0 + 64 + srow) * K + scol * 8;
  u16* lA0 = &As[0][srow * 32 + scol * 8];
  u16* lA1 = &As[0][(64 + srow) * 32 + scol * 8];
  u16* lB0 = &Bs[0][srow * 32 + scol * 8];
  u16* lB1 = &Bs[0][(64 + srow) * 32 + scol * 8];

  f32x4 acc[4][4] = {};

  auto STAGE = [&](int buf, int k0) {
    int o = buf * (128 * 32);
    gload16(gA0 + k0, lA0 + o);
    gload16(gA1 + k0, lA1 + o);
    gload16(gB0 + k0, lB0 + o);
    gload16(gB1 + k0, lB1 + o);
  };
  auto COMPUTE = [&](int buf) {
    short8 af[4], bfr[4];
    for (int i = 0; i < 4; i++)
      af[i] = *(const short8*)&As[buf][(wm * 64 + i * 16 + rq) * 32 + g4 * 8];
    for (int j = 0; j < 4; j++)
      bfr[j] = *(const short8*)&Bs[buf][(wn * 64 + j * 16 + rq) * 32 + g4 * 8];
    __builtin_amdgcn_s_setprio(1);
    for (int i = 0; i < 4; i++)
      for (int j = 0; j < 4; j++)
        acc[i][j] = __builtin_amdgcn_mfma_f32_16x16x32_bf16(af[i], bfr[j], acc[i][j], 0, 0, 0);
    __builtin_amdgcn_s_setprio(0);
  };

  const int nk = K >> 5;
  STAGE(0, 0);
  int cur = 0;
  for (int t = 0; t < nk - 1; t++) {
    STAGE(cur ^ 1, (t + 1) << 5);
    // wait only for the CURRENT tile's 4 loads; next tile's 4 stay in flight
    asm volatile("s_waitcnt vmcnt(4)" ::: "memory");
    __builtin_amdgcn_s_barrier();
    COMPUTE(cur);
    __builtin_amdgcn_s_barrier();
    cur ^= 1;
  }
  asm volatile("s_waitcnt vmcnt(0)" ::: "memory");
  __builtin_amdgcn_s_barrier();
  COMPUTE(cur);

  for (int j = 0; j < 4; j++) {
    int n = n0 + wn * 64 + j * 16 + rq;
    float bv = bias[n];
    for (int i = 0; i < 4; i++) {
      int mb = m0 + wm * 64 + i * 16 + g4 * 4;
      f32x4 v = acc[i][j];
      if (MODE == 3) {
        int b = mb >> 10, sp = mb & 1023;
        size_t off = ((size_t)b * 640 + n) * 1024 + sp;
        f32x4 xv = *(const f32x4*)(res + off);
        f32x4 o;
        for (int r = 0; r < 4; r++) o[r] = v[r] + bv + xv[r];
        *(f32x4*)((float*)outp + off) = o;
      } else {
        for (int r = 0; r < 4; r++) {
          int m = mb + r;
          if (m >= M) break;
          size_t off = (size_t)m * N + n;
          float val = v[r] + bv;
          if (MODE == 0)
            ((float*)outp)[off] = val;
          else if (MODE == 1)
            ((u16*)outp)[off] = f2bf(val);
          else if (MODE == 2)
            ((float*)outp)[off] = val + res[off];
          else  // MODE 4
            ((u16*)outp)[off] = f2bf(val + res[off]);
        }
      }
    }
  }
}

// ---------- flash attention: HD=80 (padded 96), 64 queries/block, 4 waves ----------
__global__ __launch_bounds__(256) void attn_kernel(const u16* __restrict__ Qb, int ldq, long qbs,
                                                   const u16* __restrict__ Kb, int ldk, long kbs,
                                                   const u16* __restrict__ Vb,
                                                   u16* __restrict__ Ob, int ldo, long obs,
                                                   int Sk, float scale) {
  __shared__ __align__(16) u16 Ks[64 * 104];   // [key][d pad 96->104]
  __shared__ __align__(16) u16 Vt[80 * 72];    // [d][key pad 64->72]
  __shared__ __align__(16) u16 Ps[4][16 * 72]; // per-wave P, [q][key pad]
  const short8 zero = {0, 0, 0, 0, 0, 0, 0, 0};
  const int tid = threadIdx.x;
  const int lane = tid & 63, w = tid >> 6;
  const int rq = lane & 15, g4 = lane >> 4;
  const int b = blockIdx.z, h = blockIdx.y;
  const u16* Q = Qb + (size_t)b * qbs + h * 80;
  const u16* Kp = Kb + (size_t)b * kbs + h * 80;
  const u16* Vp = Vb + (size_t)b * kbs + h * 80;
  u16* Op = Ob + (size_t)b * obs + h * 80;
  const int q0 = blockIdx.x * 64 + w * 16;

  short8 qa[3];
  for (int kk = 0; kk < 3; kk++) {
    int d = kk * 32 + g4 * 8;
    if (d < 80)
      qa[kk] = *(const short8*)(Q + (size_t)(q0 + rq) * ldq + d);
    else
      qa[kk] = zero;
  }
  f32x4 oacc[5] = {};
  float m_run[4], l_run[4];
  for (int r = 0; r < 4; r++) { m_run[r] = -1e30f; l_run[r] = 0.f; }

  const int nkt = (Sk + 63) >> 6;
  for (int kt = 0; kt < nkt; kt++) {
    // stage K tile [64][96] (zero-pad d>=80 and key>=Sk)
    for (int s = tid; s < 768; s += 256) {
      int row = s / 12, c = s % 12;
      int kidx = kt * 64 + row;
      short8 v = zero;
      if (c < 10 && kidx < Sk) v = *(const short8*)(Kp + (size_t)kidx * ldk + c * 8);
      *(short8*)&Ks[row * 104 + c * 8] = v;
    }
    // stage V^T [80][64]
    for (int s = tid; s < 640; s += 256) {
      int k = s & 63, c = s >> 6;
      int kidx = kt * 64 + k;
      short8 v = zero;
      if (kidx < Sk) v = *(const short8*)(Vp + (size_t)kidx * ldk + c * 8);
      for (int jj = 0; jj < 8; jj++) Vt[(c * 8 + jj) * 72 + k] = (u16)v[jj];
    }
    __syncthreads();

    // scores: 16 q x 64 k per wave
    f32x4 sc[4] = {};
    for (int n = 0; n < 4; n++)
      for (int kk = 0; kk < 3; kk++) {
        short8 kb = *(const short8*)&Ks[(n * 16 + rq) * 104 + kk * 32 + g4 * 8];
        sc[n] = __builtin_amdgcn_mfma_f32_16x16x32_bf16(qa[kk], kb, sc[n], 0, 0, 0);
      }
    int kbase = kt * 64;
    for (int n = 0; n < 4; n++) {
      sc[n] *= scale;
      if (kbase + n * 16 + rq >= Sk)
        for (int r = 0; r < 4; r++) sc[n][r] = -1e30f;
    }
    float tm[4];
    for (int r = 0; r < 4; r++)
      tm[r] = fmaxf(fmaxf(sc[0][r], sc[1][r]), fmaxf(sc[2][r], sc[3][r]));
    for (int off = 1; off < 16; off <<= 1)
      for (int r = 0; r < 4; r++) tm[r] = fmaxf(tm[r], __shfl_xor(tm[r], off));
    float sf[4], rs[4];
    for (int r = 0; r < 4; r++) {
      float mn = fmaxf(m_run[r], tm[r]);
      sf[r] = __expf(m_run[r] - mn);
      m_run[r] = mn;
      rs[r] = 0.f;
    }
    for (int n = 0; n < 4; n++)
      for (int r = 0; r < 4; r++) {
        float pv = __expf(sc[n][r] - m_run[r]);
        sc[n][r] = pv;
        rs[r] += pv;
      }
    for (int off = 1; off < 16; off <<= 1)
      for (int r = 0; r < 4; r++) rs[r] += __shfl_xor(rs[r], off);
    for (int r = 0; r < 4; r++) l_run[r] = l_run[r] * sf[r] + rs[r];
    for (int nn = 0; nn < 5; nn++)
      for (int r = 0; r < 4; r++) oacc[nn][r] *= sf[r];
    // P -> LDS (bf16), per-wave buffer
    for (int n = 0; n < 4; n++)
      for (int r = 0; r < 4; r++)
        Ps[w][(g4 * 4 + r) * 72 + n * 16 + rq] = f2bf(sc[n][r]);
    __syncthreads();
    // PV
    for (int s = 0; s < 2; s++) {
      short8 pa = *(const short8*)&Ps[w][rq * 72 + s * 32 + g4 * 8];
      for (int nn = 0; nn < 5; nn++) {
        short8 vb = *(const short8*)&Vt[(nn * 16 + rq) * 72 + s * 32 + g4 * 8];
        oacc[nn] = __builtin_amdgcn_mfma_f32_16x16x32_bf16(pa, vb, oacc[nn], 0, 0, 0);
      }
    }
    __syncthreads();
  }
  for (int nn = 0; nn < 5; nn++)
    for (int r = 0; r < 4; r++) {
      float v = oacc[nn][r] / l_run[r];
      Op[(size_t)(q0 + g4 * 4 + r) * ldo + nn * 16 + rq] = f2bf(v);
    }
}

extern "C" void kernel_launch(void* const* d_in, const int* in_sizes, int n_in,
                              void* d_out, int out_size, void* d_ws, size_t ws_size,
                              hipStream_t stream) {
  (void)in_sizes; (void)n_in; (void)out_size; (void)ws_size;
  const float* x = (const float*)d_in[0];
  const float* p = (const float*)d_in[1];
  const float* gn_g = (const float*)d_in[2];
  const float* gn_b = (const float*)d_in[3];
  const float* ci_w = (const float*)d_in[4];
  const float* ci_b = (const float*)d_in[5];
  const float* ln1_g = (const float*)d_in[6];
  const float* ln1_b = (const float*)d_in[7];
  const float* qkv_w = (const float*)d_in[8];
  const float* qkv_b = (const float*)d_in[9];
  const float* saw_w = (const float*)d_in[10];
  const float* saw_b = (const float*)d_in[11];
  const float* ln2_g = (const float*)d_in[12];
  const float* ln2_b = (const float*)d_in[13];
  const float* caq_w = (const float*)d_in[14];
  const float* caq_b = (const float*)d_in[15];
  const float* cak_w = (const float*)d_in[16];
  const float* cak_b = (const float*)d_in[17];
  const float* cav_w = (const float*)d_in[18];
  const float* cav_b = (const float*)d_in[19];
  const float* caw_w = (const float*)d_in[20];
  const float* caw_b = (const float*)d_in[21];
  const float* ln3_g = (const float*)d_in[22];
  const float* ln3_b = (const float*)d_in[23];
  const float* g1_w = (const float*)d_in[24];
  const float* g1_b = (const float*)d_in[25];
  const float* g2_w = (const float*)d_in[26];
  const float* g2_b = (const float*)d_in[27];
  const float* co_w = (const float*)d_in[28];
  const float* co_b = (const float*)d_in[29];
  float* out = (float*)d_out;

  char* ws = (char*)d_ws;
  size_t off = 0;
  auto alloc = [&](size_t bytes) {
    size_t o = off;
    off += (bytes + 255) & ~(size_t)255;
    return o;
  };
  u16* WCI = (u16*)(ws + alloc((size_t)640 * 640 * 2));
  u16* WQKV = (u16*)(ws + alloc((size_t)1920 * 640 * 2));
  u16* WSAW = (u16*)(ws + alloc((size_t)640 * 640 * 2));
  u16* WCAQ = (u16*)(ws + alloc((size_t)640 * 640 * 2));
  u16* WCAK = (u16*)(ws + alloc((size_t)640 * 512 * 2));
  u16* WCAV = (u16*)(ws + alloc((size_t)640 * 512 * 2));
  u16* WCAW = (u16*)(ws + alloc((size_t)640 * 640 * 2));
  u16* WG1 = (u16*)(ws + alloc((size_t)5120 * 640 * 2));
  u16* WG2 = (u16*)(ws + alloc((size_t)640 * 2560 * 2));
  u16* WCO = (u16*)(ws + alloc((size_t)640 * 640 * 2));
  u16* X = (u16*)(ws + alloc((size_t)8192 * 640 * 2));
  u16* Y = (u16*)(ws + alloc((size_t)8192 * 640 * 2));
  float* F1 = (float*)(ws + alloc((size_t)8192 * 640 * 4));
  u16* QKV = (u16*)(ws + alloc((size_t)8192 * 1920 * 2));
  u16* PBF = (u16*)(ws + alloc((size_t)616 * 512 * 2));
  u16* KC = (u16*)(ws + alloc((size_t)616 * 640 * 2));
  u16* VC = (u16*)(ws + alloc((size_t)616 * 640 * 2));
  u16* PROJ = (u16*)(ws + alloc((size_t)8192 * 5120 * 2));
  u16* TG = (u16*)(ws + alloc((size_t)8192 * 2560 * 2));
  float* GNM = (float*)(ws + alloc(256 * 4));
  float* GNR = (float*)(ws + alloc(256 * 4));

  // ---- merged weight prep (transpose to [N][K] bf16) ----
  PrepArgs pa;
  int boff = 0;
  auto addw = [&](int idx, const float* src, u16* dst, int K, int N) {
    pa.d[idx].src = src; pa.d[idx].dst = dst;
    pa.d[idx].K = K; pa.d[idx].N = N;
    pa.d[idx].nbx = N / 32; pa.d[idx].boff = boff;
    boff += (N / 32) * (K / 32);
  };
  addw(0, ci_w, WCI, 640, 640);
  addw(1, qkv_w, WQKV, 640, 1920);
  addw(2, saw_w, WSAW, 640, 640);
  addw(3, caq_w, WCAQ, 640, 640);
  addw(4, cak_w, WCAK, 512, 640);
  addw(5, cav_w, WCAV, 512, 640);
  addw(6, caw_w, WCAW, 640, 640);
  addw(7, g1_w, WG1, 640, 5120);
  addw(8, g2_w, WG2, 2560, 640);
  addw(9, co_w, WCO, 640, 640);
  prep_all<<<boff, 256, 0, stream>>>(pa);
  conv_bf16<<<1232, 256, 0, stream>>>(p, PBF, (long)616 * 512);

  // ---- groupnorm + transpose to token-major bf16 ----
  gn_stats<<<256, 256, 0, stream>>>(x, GNM, GNR);
  gn_apply<<<dim3(32, 20, 8), 256, 0, stream>>>(x, GNM, GNR, gn_g, gn_b, X);

  const float scale = 0.11180339887498949f;  // 1/sqrt(80)

  // conv_input
  gemm_bt<0><<<dim3(64, 5), 256, 0, stream>>>(X, WCI, ci_b, F1, nullptr, 8192, 640, 640);
  // self-attention
  ln_kernel<<<2048, 256, 0, stream>>>(F1, ln1_g, ln1_b, Y);
  gemm_bt<1><<<dim3(64, 15), 256, 0, stream>>>(Y, WQKV, qkv_b, QKV, nullptr, 8192, 1920, 640);
  attn_kernel<<<dim3(16, 8, 8), 256, 0, stream>>>(QKV, 1920, (long)1024 * 1920,
                                                  QKV + 640, 1920, (long)1024 * 1920,
                                                  QKV + 1280, X, 640, (long)1024 * 640,
                                                  1024, scale);
  gemm_bt<2><<<dim3(64, 5), 256, 0, stream>>>(X, WSAW, saw_b, F1, F1, 8192, 640, 640);
  // cross-attention
  ln_kernel<<<2048, 256, 0, stream>>>(F1, ln2_g, ln2_b, Y);
  gemm_bt<1><<<dim3(64, 5), 256, 0, stream>>>(Y, WCAQ, caq_b, X, nullptr, 8192, 640, 640);
  gemm_bt<1><<<dim3(5, 5), 256, 0, stream>>>(PBF, WCAK, cak_b, KC, nullptr, 616, 640, 512);
  gemm_bt<1><<<dim3(5, 5), 256, 0, stream>>>(PBF, WCAV, cav_b, VC, nullptr, 616, 640, 512);
  attn_kernel<<<dim3(16, 8, 8), 256, 0, stream>>>(X, 640, (long)1024 * 640,
                                                  KC, 640, (long)77 * 640,
                                                  VC, Y, 640, (long)1024 * 640,
                                                  77, scale);
  gemm_bt<2><<<dim3(64, 5), 256, 0, stream>>>(Y, WCAW, caw_b, F1, F1, 8192, 640, 640);
  // GEGLU MLP
  ln_kernel<<<2048, 256, 0, stream>>>(F1, ln3_g, ln3_b, X);
  gemm_bt<1><<<dim3(64, 40), 256, 0, stream>>>(X, WG1, g1_b, PROJ, nullptr, 8192, 5120, 640);
  geglu<<<10240, 256, 0, stream>>>(PROJ, TG);
  // g2 with fused bf16 conversion of (acc + bias + res) -> X
  gemm_bt<4><<<dim3(64, 5), 256, 0, stream>>>(TG, WG2, g2_b, X, F1, 8192, 640, 2560);
  // conv_output + long residual (transposed store)
  gemm_bt<3><<<dim3(64, 5), 256, 0, stream>>>(X, WCO, co_b, out, x, 8192, 640, 640);
}